// Round 11
// baseline (103.753 us; speedup 1.0000x reference)
//
#include <hip/hip_runtime.h>
#include <hip/hip_bf16.h>

constexpr int BATCH = 256;
constexpr int VOCAB = 128000;
constexpr int K = 256;
constexpr float IGNORED_C = -3000.0f;

// fast path params
constexpr int NCHUNK = 8;
constexpr int CHUNK = VOCAB / NCHUNK;   // 16000
constexpr int N4 = CHUNK / 4;           // 4000 float4 per chunk
constexpr int BINS = 8192;              // top 13 bits of monotone key
constexpr int SHIFT = 19;
constexpr int CAP = 1024;               // candidate cap (LDS sort width)
constexpr unsigned SGOAL = 46;          // 1/8-sample suffix goal: E[true]~368

// fallback path params
constexpr int FB_BINS = 8192;
constexpr int FB_SHIFT = 19;
constexpr int FB_CAND = 2048;

// order-preserving f32 -> u32 map (larger float => larger key)
__device__ __forceinline__ unsigned mono(unsigned u) {
    return (u & 0x80000000u) ? ~u : (u | 0x80000000u);
}
__device__ __forceinline__ float inv_mono(unsigned k) {
    unsigned u = (k & 0x80000000u) ? (k ^ 0x80000000u) : ~k;
    return __uint_as_float(u);
}

// ============================================================================
// K1: per (row, chunk): 1/8-SAMPLE packed-u16 LDS histogram -> wave-0 suffix
// scan -> threshold bin -> full-stream collect (exact count verify) ->
// LDS bitonic sort-1024 -> sorted top-256 u64 keys.
// R10 post-mortem: full histogram = 128K LDS atomics/CU ~= 53 us invariant
// floor. 1/8 sample cuts that 8x; exactness preserved by count verification
// with a key-space binary-search fallback (streams from L2, ~never taken).
// ============================================================================
__global__ __launch_bounds__(512)
void k1_topk_chunk(const float* __restrict__ logits,
                   unsigned long long* __restrict__ ws_cand)
{
    __shared__ unsigned hist[BINS / 2];          // packed 2 x 16-bit counters
    __shared__ unsigned part[512];
    __shared__ unsigned long long cand[CAP];
    __shared__ unsigned wred[16];
    __shared__ unsigned ccount;
    __shared__ int s_tbin;

    const int tid = threadIdx.x;
    const int wave = tid >> 6, lane = tid & 63;
    const int row = blockIdx.x >> 3;            // NCHUNK == 8
    const int chunk = blockIdx.x & 7;
    const int gbase = chunk * CHUNK;
    const float4* rp4 = reinterpret_cast<const float4*>(
        logits + (size_t)row * VOCAB + (size_t)gbase);

    for (int i = tid; i < BINS / 2; i += 512) hist[i] = 0u;
    if (tid == 0) ccount = 0u;
    __syncthreads();

    // ---- pass 1: histogram a contiguous-run 1/8 sample (500 float4s:
    //      4 runs of 125 at offsets 0/1000/2000/3000 -> coalesced) ----
    if (tid < 500) {
        const int seg = tid / 125, off = tid % 125;
        const float4 v = rp4[seg * 1000 + off];
        unsigned b;
        b = mono(__float_as_uint(v.x)) >> SHIFT; atomicAdd(&hist[b >> 1], 1u << ((b & 1) * 16));
        b = mono(__float_as_uint(v.y)) >> SHIFT; atomicAdd(&hist[b >> 1], 1u << ((b & 1) * 16));
        b = mono(__float_as_uint(v.z)) >> SHIFT; atomicAdd(&hist[b >> 1], 1u << ((b & 1) * 16));
        b = mono(__float_as_uint(v.w)) >> SHIFT; atomicAdd(&hist[b >> 1], 1u << ((b & 1) * 16));
    }
    __syncthreads();

    // ---- group sums of 16 bins (8 packed words) each, rotated reads ----
    {
        unsigned s = 0;
        #pragma unroll
        for (int j = 0; j < 8; ++j) {
            const unsigned w = hist[tid * 8 + ((j + tid) & 7)];
            s += (w & 0xFFFFu) + (w >> 16);
        }
        part[tid] = s;
    }
    __syncthreads();

    // ---- wave 0: suffix scan over 512 group sums -> threshold bin
    //      tb = max bin with sample_suffix(tb) >= SGOAL ----
    if (tid < 64) {
        const int l = tid;
        const unsigned g0 = part[l * 8 + 0], g1 = part[l * 8 + 1];
        const unsigned g2 = part[l * 8 + 2], g3 = part[l * 8 + 3];
        const unsigned g4 = part[l * 8 + 4], g5 = part[l * 8 + 5];
        const unsigned g6 = part[l * 8 + 6], g7 = part[l * 8 + 7];
        const unsigned s7 = g7;
        const unsigned s6 = s7 + g6;
        const unsigned s5 = s6 + g5;
        const unsigned s4 = s5 + g4;
        const unsigned s3 = s4 + g3;
        const unsigned s2 = s3 + g2;
        const unsigned s1 = s2 + g1;
        const unsigned s0 = s1 + g0;        // lane total
        unsigned suf = s0;                  // inclusive suffix across lanes
        #pragma unroll
        for (int off = 1; off < 64; off <<= 1) {
            unsigned t = __shfl_down(suf, off);
            if (l + off < 64) suf += t;
        }
        const unsigned hi = suf - s0;       // sum over lanes > l
        const bool finder = (hi < SGOAL) && (hi + s0 >= SGOAL);
        int jj; unsigned base;
        if      (hi + s7 >= SGOAL) { jj = 7; base = hi; }
        else if (hi + s6 >= SGOAL) { jj = 6; base = hi + s7; }
        else if (hi + s5 >= SGOAL) { jj = 5; base = hi + s6; }
        else if (hi + s4 >= SGOAL) { jj = 4; base = hi + s5; }
        else if (hi + s3 >= SGOAL) { jj = 3; base = hi + s4; }
        else if (hi + s2 >= SGOAL) { jj = 2; base = hi + s3; }
        else if (hi + s1 >= SGOAL) { jj = 1; base = hi + s2; }
        else                       { jj = 0; base = hi + s1; }
        int tg = l * 8 + jj;
        const unsigned long long fm = __ballot(finder);
        const int src = __ffsll((unsigned long long)fm) - 1;
        tg   = __shfl(tg, src);
        base = __shfl(base, src);
        unsigned h = 0u;
        if (l < 16) {
            const unsigned w = hist[tg * 8 + (l >> 1)];
            h = (w >> ((l & 1) * 16)) & 0xFFFFu;
        }
        unsigned suf16 = h;
        #pragma unroll
        for (int off = 1; off < 16; off <<= 1) {
            unsigned t = __shfl_down(suf16, off);
            if (l + off < 16) suf16 += t;
        }
        const bool qual = (l < 16) && (base + suf16 >= SGOAL);
        const unsigned long long qm = __ballot(qual);
        if (l == 0) s_tbin = tg * 16 + (63 - __builtin_clzll(qm));
    }
    __syncthreads();

    // ---- pass 2: full-stream collect with bin >= tb; ccount = exact n_ge ----
    const unsigned tb = (unsigned)s_tbin;
#define COLV(vv, off4) { \
    const unsigned k_ = mono(__float_as_uint(vv)); \
    if ((k_ >> SHIFT) >= tb) { \
        const unsigned p_ = atomicAdd(&ccount, 1u); \
        if (p_ < (unsigned)CAP) \
            cand[p_] = ((unsigned long long)k_ << 32) | (unsigned)(~(off4)); \
    } }
    for (int i = tid; i < N4; i += 1024) {
        const float4 va = rp4[i];
        const bool hb = (i + 512) < N4;
        float4 vb;
        if (hb) vb = rp4[i + 512];
        const int ba = gbase + i * 4;
        COLV(va.x, ba + 0) COLV(va.y, ba + 1) COLV(va.z, ba + 2) COLV(va.w, ba + 3)
        if (hb) {
            const int bb = gbase + (i + 512) * 4;
            COLV(vb.x, bb + 0) COLV(vb.y, bb + 1) COLV(vb.z, bb + 2) COLV(vb.w, bb + 3)
        }
    }
#undef COLV
    __syncthreads();
    unsigned cc = ccount;
    __syncthreads();

    // ---- exact fallback (block-uniform, ~never taken): key-space search ----
#define COUNT_KEY(Tv, Xv, NGT, NEQ) do { \
    const unsigned T_ = (Tv), X_ = (Xv); \
    unsigned cgt = 0u, ceq = 0u; \
    for (int i_ = tid; i_ < N4; i_ += 512) { \
        const float4 v_ = rp4[i_]; \
        const unsigned b_ = 4u * (unsigned)i_; \
        unsigned kk_; \
        kk_ = mono(__float_as_uint(v_.x)); cgt += (kk_ > T_); ceq += ((kk_ == T_) && (b_ + 0u <= X_)); \
        kk_ = mono(__float_as_uint(v_.y)); cgt += (kk_ > T_); ceq += ((kk_ == T_) && (b_ + 1u <= X_)); \
        kk_ = mono(__float_as_uint(v_.z)); cgt += (kk_ > T_); ceq += ((kk_ == T_) && (b_ + 2u <= X_)); \
        kk_ = mono(__float_as_uint(v_.w)); cgt += (kk_ > T_); ceq += ((kk_ == T_) && (b_ + 3u <= X_)); \
    } \
    for (int o_ = 32; o_ >= 1; o_ >>= 1) { cgt += __shfl_xor(cgt, o_); ceq += __shfl_xor(ceq, o_); } \
    __syncthreads(); \
    if (lane == 0) { wred[wave] = cgt; wred[8 + wave] = ceq; } \
    __syncthreads(); \
    unsigned g_ = 0u, e_ = 0u; \
    for (int w_ = 0; w_ < 8; ++w_) { g_ += wred[w_]; e_ += wred[8 + w_]; } \
    (NGT) = g_; (NEQ) = e_; \
} while (0)

    if (cc < (unsigned)K || cc > (unsigned)CAP) {
        unsigned g, e, T;
        bool tie = false; unsigned X = 0xFFFFFFFFu;
        COUNT_KEY(0xFFFFFFFFu, 0xFFFFFFFFu, g, e);
        if (g + e >= (unsigned)K) {
            T = 0xFFFFFFFFu;                     // degenerate: everything at max
        } else {
            unsigned klo = 0u, khi = 0xFFFFFFFFu;  // n_ge(0)=CHUNK>=K; n_ge(max)<K
            while (khi - klo > 1u) {
                const unsigned mid = klo + ((khi - klo) >> 1);
                COUNT_KEY(mid, 0xFFFFFFFFu, g, e);
                if (g + e >= (unsigned)K) klo = mid; else khi = mid;
            }
            T = klo;
        }
        COUNT_KEY(T, 0xFFFFFFFFu, g, e);
        if (g + e > (unsigned)CAP) {
            tie = true;
            const unsigned target = (unsigned)K - g;   // g < K by maximality of T
            int xlo = -1, xhi = CHUNK - 1;
            while (xhi - xlo > 1) {
                const int xm = (xlo + xhi) >> 1;
                unsigned g2, e2;
                COUNT_KEY(T, (unsigned)xm, g2, e2);
                if (e2 >= target) xhi = xm; else xlo = xm;
            }
            X = (unsigned)xhi;
        }
        if (tid == 0) ccount = 0u;
        __syncthreads();
        for (int i = tid; i < N4; i += 512) {
            const float4 v = rp4[i];
            const unsigned b = 4u * (unsigned)i;
#define FCOL(kx, off) { \
        const unsigned kk_ = (kx); \
        if ((kk_ > T) || ((kk_ == T) && (!tie || (b + (off)) <= X))) { \
            const unsigned p_ = atomicAdd(&ccount, 1u); \
            if (p_ < (unsigned)CAP) \
                cand[p_] = ((unsigned long long)kk_ << 32) \
                         | (unsigned)(~(unsigned)(gbase + (int)(b + (off)))); \
        } }
            FCOL(mono(__float_as_uint(v.x)), 0u)
            FCOL(mono(__float_as_uint(v.y)), 1u)
            FCOL(mono(__float_as_uint(v.z)), 2u)
            FCOL(mono(__float_as_uint(v.w)), 3u)
#undef FCOL
        }
        __syncthreads();
        cc = ccount;
        __syncthreads();
    }
#undef COUNT_KEY

    // ---- pad and LDS bitonic sort 1024 (u64), descending ----
    const unsigned stored = (cc < (unsigned)CAP) ? cc : (unsigned)CAP;
    for (int i = tid; i < CAP; i += 512)
        if ((unsigned)i >= stored) cand[i] = 0ull;
    __syncthreads();

    for (int k = 2; k <= CAP; k <<= 1) {
        for (int j = k >> 1; j > 0; j >>= 1) {
            for (int i = tid; i < CAP; i += 512) {
                const int ixj = i ^ j;
                if (ixj > i) {
                    const unsigned long long a = cand[i], b = cand[ixj];
                    const bool sw = ((i & k) == 0) ? (a < b) : (a > b);
                    if (sw) { cand[i] = b; cand[ixj] = a; }
                }
            }
            __syncthreads();
        }
    }

    if (tid < K) ws_cand[(size_t)blockIdx.x * K + tid] = cand[tid];
}

// ============================================================================
// K2: per row merge 8 sorted runs (bitonic merge stages only) + pipeline
// (proven: ~1-2 us)
// ============================================================================
__global__ __launch_bounds__(1024)
void k2_merge(const float* __restrict__ params,
              const unsigned long long* __restrict__ ws_cand,
              float* __restrict__ ws_v, float* __restrict__ ws_csum,
              int* __restrict__ ws_idx, float* __restrict__ ws_p0)
{
    constexpr int N = NCHUNK * K;   // 2048
    __shared__ unsigned long long cand[N];
    __shared__ float red[K];
    __shared__ float sc[K];

    const int row = blockIdx.x;
    const int tid = threadIdx.x;

    // load; reverse odd runs so runs alternate desc/asc (valid bitonic state k=256)
    for (int i = tid; i < N; i += 1024) {
        const int c = i >> 8, pos = i & (K - 1);
        unsigned long long v = ws_cand[(size_t)row * N + i];
        const int dest = (c & 1) ? ((c << 8) | (K - 1 - pos)) : i;
        cand[dest] = v;
    }
    __syncthreads();

    // bitonic merge stages k = 512, 1024, 2048 (descending overall)
    for (int kk2 = 2 * K; kk2 <= N; kk2 <<= 1) {
        for (int j = kk2 >> 1; j > 0; j >>= 1) {
            for (int i = tid; i < N; i += 1024) {
                const int ixj = i ^ j;
                if (ixj > i) {
                    unsigned long long a = cand[i], b = cand[ixj];
                    bool sw = ((i & kk2) == 0) ? (a < b) : (a > b);
                    if (sw) { cand[i] = b; cand[ixj] = a; }
                }
            }
            __syncthreads();
        }
    }

    // pipeline on top-256: topk-mask -> /temp -> softmax -> cumsum
    const bool act = tid < K;
    const float topk_f = params[row * 3 + 0];
    const float temp   = params[row * 3 + 2];
    float v = 0.f;
    int myidx = 0;
    if (act) {
        unsigned long long c = cand[tid];
        float val = inv_mono((unsigned)(c >> 32));
        myidx = (int)(~(unsigned)c);
        float x = (((float)tid) >= topk_f) ? IGNORED_C : val;
        v = x / temp;
        red[tid] = v;
    }
    __syncthreads();
    for (int s = K / 2; s > 0; s >>= 1) {
        if (tid < s) red[tid] = fmaxf(red[tid], red[tid + s]);
        __syncthreads();
    }
    const float m = red[0];
    __syncthreads();
    const float e = act ? expf(v - m) : 0.f;
    if (act) red[tid] = e;
    __syncthreads();
    for (int s = K / 2; s > 0; s >>= 1) {
        if (tid < s) red[tid] += red[tid + s];
        __syncthreads();
    }
    const float ssum = red[0];
    __syncthreads();
    const float p = e / ssum;
    if (act) sc[tid] = p;
    __syncthreads();
    for (int off = 1; off < K; off <<= 1) {
        float t = 0.f;
        if (act && tid >= off) t = sc[tid - off];
        __syncthreads();
        if (act) sc[tid] += t;
        __syncthreads();
    }
    if (act) {
        ws_v[row * K + tid]    = v;
        ws_csum[row * K + tid] = sc[tid];
        ws_idx[row * K + tid]  = myidx;
    }
    if (tid == 0) ws_p0[row] = p;   // probs[0] == csum[0]
}

// ============================================================================
// K3: global-min(p0) -> top-p mask -> softmax -> cumsum -> sample
// ============================================================================
__global__ __launch_bounds__(K)
void k3_sample(const float* __restrict__ params,
               const float* __restrict__ rand_u,
               const float* __restrict__ ws_v,
               const float* __restrict__ ws_csum,
               const int* __restrict__ ws_idx,
               const float* __restrict__ ws_p0,
               int* __restrict__ out)
{
    __shared__ float red[K];
    __shared__ float sc[K];
    const int row = blockIdx.x;
    const int tid = threadIdx.x;

    red[tid] = ws_p0[tid];          // BATCH == 256 == blockDim
    __syncthreads();
    for (int s = K / 2; s > 0; s >>= 1) {
        if (tid < s) red[tid] = fminf(red[tid], red[tid + s]);
        __syncthreads();
    }
    const float tpe = fmaxf(red[0], params[row * 3 + 1]);
    __syncthreads();

    const float csum = ws_csum[row * K + tid];
    const float v0   = ws_v[row * K + tid];
    const float v2 = ((csum > tpe) && (tid != 0)) ? IGNORED_C : v0;
    red[tid] = v2;
    __syncthreads();
    for (int s = K / 2; s > 0; s >>= 1) {
        if (tid < s) red[tid] = fmaxf(red[tid], red[tid + s]);
        __syncthreads();
    }
    const float m = red[0];
    __syncthreads();
    const float e = expf(v2 - m);
    red[tid] = e;
    __syncthreads();
    for (int s = K / 2; s > 0; s >>= 1) {
        if (tid < s) red[tid] += red[tid + s];
        __syncthreads();
    }
    const float ssum = red[0];
    __syncthreads();
    const float p = e / ssum;
    sc[tid] = p;
    __syncthreads();
    for (int off = 1; off < K; off <<= 1) {
        float t = (tid >= off) ? sc[tid - off] : 0.f;
        __syncthreads();
        sc[tid] += t;
        __syncthreads();
    }
    const float ru = rand_u[row];
    red[tid] = (ru > sc[tid]) ? 1.f : 0.f;
    __syncthreads();
    for (int s = K / 2; s > 0; s >>= 1) {
        if (tid < s) red[tid] += red[tid + s];
        __syncthreads();
    }
    if (tid == 0) {
        int sel = (int)red[0];
        if (sel > K - 1) sel = K - 1;
        out[row] = ws_idx[row * K + sel];
    }
}

// ============================================================================
// Fallback (round-1 proven): single block per row, used only if ws too small
// ============================================================================
__global__ __launch_bounds__(1024)
void fb_stage1(const float* __restrict__ logits,
               const float* __restrict__ params,
               float* __restrict__ ws_v,
               float* __restrict__ ws_csum,
               int* __restrict__ ws_idx,
               float* __restrict__ ws_p0)
{
    __shared__ unsigned hist[FB_BINS];
    __shared__ unsigned gsum[128];
    __shared__ unsigned long long cand[FB_CAND];
    __shared__ unsigned ccount;
    __shared__ int tbin;
    __shared__ float sv[K];
    __shared__ float se[K];
    __shared__ int   sidx[K];
    __shared__ float sred;

    const int row = blockIdx.x;
    const int tid = threadIdx.x;
    const float4* rp4 = reinterpret_cast<const float4*>(logits + (size_t)row * VOCAB);

    for (int i = tid; i < FB_BINS; i += 1024) hist[i] = 0u;
    __syncthreads();
    for (int i = tid; i < VOCAB / 4; i += 1024) {
        float4 v = rp4[i];
        atomicAdd(&hist[mono(__float_as_uint(v.x)) >> FB_SHIFT], 1u);
        atomicAdd(&hist[mono(__float_as_uint(v.y)) >> FB_SHIFT], 1u);
        atomicAdd(&hist[mono(__float_as_uint(v.z)) >> FB_SHIFT], 1u);
        atomicAdd(&hist[mono(__float_as_uint(v.w)) >> FB_SHIFT], 1u);
    }
    __syncthreads();
    if (tid < 128) {
        unsigned s = 0;
        for (int i = 0; i < 64; ++i) s += hist[tid * 64 + i];
        gsum[tid] = s;
    }
    __syncthreads();
    if (tid == 0) {
        unsigned acc = 0;
        int g = 127;
        for (; g > 0; --g) {
            if (acc + gsum[g] >= (unsigned)K) break;
            acc += gsum[g];
        }
        int t = g * 64;
        for (int bin = g * 64 + 63; bin >= g * 64; --bin) {
            acc += hist[bin];
            if (acc >= (unsigned)K) { t = bin; break; }
        }
        tbin = t;
        ccount = 0u;
    }
    __syncthreads();
    const unsigned tb = (unsigned)tbin;
    for (int i = tid; i < VOCAB / 4; i += 1024) {
        float4 v = rp4[i];
        const int base = i * 4;
        unsigned kk[4] = { mono(__float_as_uint(v.x)), mono(__float_as_uint(v.y)),
                           mono(__float_as_uint(v.z)), mono(__float_as_uint(v.w)) };
        #pragma unroll
        for (int c = 0; c < 4; ++c) {
            if ((kk[c] >> FB_SHIFT) >= tb) {
                unsigned p = atomicAdd(&ccount, 1u);
                if (p < FB_CAND)
                    cand[p] = ((unsigned long long)kk[c] << 32) | (unsigned)(~(base + c));
            }
        }
    }
    __syncthreads();
    for (int i = tid; i < FB_CAND; i += 1024)
        if ((unsigned)i >= ccount) cand[i] = 0ull;
    __syncthreads();
    for (int k = 2; k <= FB_CAND; k <<= 1) {
        for (int j = k >> 1; j > 0; j >>= 1) {
            for (int i = tid; i < FB_CAND; i += 1024) {
                int ixj = i ^ j;
                if (ixj > i) {
                    unsigned long long a = cand[i], b = cand[ixj];
                    bool sw = ((i & k) == 0) ? (a < b) : (a > b);
                    if (sw) { cand[i] = b; cand[ixj] = a; }
                }
            }
            __syncthreads();
        }
    }
    const float topk_f = params[row * 3 + 0];
    const float temp   = params[row * 3 + 2];
    if (tid < K) {
        unsigned long long c = cand[tid];
        float val = inv_mono((unsigned)(c >> 32));
        sidx[tid] = (int)(~(unsigned)c);
        float v = (((float)tid) >= topk_f) ? IGNORED_C : val;
        sv[tid] = v / temp;
    }
    __syncthreads();
    if (tid == 0) {
        float mm = sv[0];
        for (int i = 1; i < K; ++i) mm = fmaxf(mm, sv[i]);
        sred = mm;
    }
    __syncthreads();
    if (tid < K) se[tid] = expf(sv[tid] - sred);
    __syncthreads();
    if (tid == 0) {
        float s = 0.f;
        for (int i = 0; i < K; ++i) s += se[i];
        sred = s;
    }
    __syncthreads();
    if (tid < K) se[tid] = se[tid] / sred;
    __syncthreads();
    if (tid == 0) {
        float c = 0.f;
        for (int i = 0; i < K; ++i) { c += se[i]; se[i] = c; }
    }
    __syncthreads();
    if (tid < K) {
        ws_v[row * K + tid]    = sv[tid];
        ws_csum[row * K + tid] = se[tid];
        ws_idx[row * K + tid]  = sidx[tid];
    }
    if (tid == 0) ws_p0[row] = se[0];
}

extern "C" void kernel_launch(void* const* d_in, const int* in_sizes, int n_in,
                              void* d_out, int out_size, void* d_ws, size_t ws_size,
                              hipStream_t stream) {
    const float* logits = (const float*)d_in[0];
    const float* params = (const float*)d_in[1];
    const float* randu  = (const float*)d_in[2];
    int* out = (int*)d_out;
    char* ws = (char*)d_ws;

    const size_t cand_bytes = (size_t)BATCH * NCHUNK * K * 8;          // 4 MB
    const size_t tail_bytes = (size_t)3 * BATCH * K * 4 + BATCH * 4;   // 769 KB
    if (ws_size >= cand_bytes + tail_bytes) {
        unsigned long long* ws_cand = (unsigned long long*)ws;
        char* p = ws + cand_bytes;
        float* ws_v    = (float*)(p);
        float* ws_csum = (float*)(p + (size_t)BATCH * K * 4);
        int*   ws_idx  = (int*)  (p + (size_t)2 * BATCH * K * 4);
        float* ws_p0   = (float*)(p + (size_t)3 * BATCH * K * 4);
        hipLaunchKernelGGL(k1_topk_chunk, dim3(BATCH * NCHUNK), dim3(512), 0, stream,
                           logits, ws_cand);
        hipLaunchKernelGGL(k2_merge, dim3(BATCH), dim3(1024), 0, stream,
                           params, ws_cand, ws_v, ws_csum, ws_idx, ws_p0);
        hipLaunchKernelGGL(k3_sample, dim3(BATCH), dim3(K), 0, stream,
                           params, randu, ws_v, ws_csum, ws_idx, ws_p0, out);
    } else {
        float* ws_v    = (float*)(ws);
        float* ws_csum = (float*)(ws + (size_t)BATCH * K * 4);
        int*   ws_idx  = (int*)  (ws + (size_t)2 * BATCH * K * 4);
        float* ws_p0   = (float*)(ws + (size_t)3 * BATCH * K * 4);
        hipLaunchKernelGGL(fb_stage1, dim3(BATCH), dim3(1024), 0, stream,
                           logits, params, ws_v, ws_csum, ws_idx, ws_p0);
        hipLaunchKernelGGL(k3_sample, dim3(BATCH), dim3(K), 0, stream,
                           params, randu, ws_v, ws_csum, ws_idx, ws_p0, out);
    }
}